// Round 1
// baseline (9820.582 us; speedup 1.0000x reference)
//
#include <hip/hip_runtime.h>
#include <hip/hip_bf16.h>
#include <math.h>

// Problem constants (from reference)
#define B_SZ 128
#define T_SZ 65536
#define F_FR 4095          // (T - 32)/16 + 1
#define GHID 64            // GRU hidden
#define HID 8
#define CHUNK 256          // fast-scan chunk length
#define NCH (T_SZ / CHUNK) // 256 chunks

__device__ __forceinline__ float sigm(float xv) { return 1.0f / (1.0f + __expf(-xv)); }
// tanh(x) = 1 - 2/(1+e^{2x}); robust at both tails for |x| <~ 40
__device__ __forceinline__ float tanh_fast(float xv) { return 1.0f - 2.0f / (1.0f + __expf(2.0f * xv)); }

// ---------------- Pass 1: per-frame GRU (slow branch) ----------------
// One thread per (b, f) sequence. h[64] lives in VGPRs (k fully unrolled).
// w_hh accessed with wave-uniform indices -> compiler emits s_load (SGPR
// operands for the FMAs). In-place update hazard (row j' needs OLD h[j])
// solved by keeping a thread-private LDS mirror: regs hold OLD h for the
// dot products; LDS slot j is read (old) then overwritten (new); end of
// step copies LDS -> regs. Pad 65: bank = (lane + j) & 31 -> conflict-free.
__global__ __launch_bounds__(256) void gru_slow(
    const float* __restrict__ x, const float* __restrict__ w_ih,
    const float* __restrict__ w_hh, const float* __restrict__ b_ih,
    const float* __restrict__ b_hh, const float* __restrict__ w_sl,
    const float* __restrict__ b_sl, float* __restrict__ ag)
{
    __shared__ float hbuf[256 * 65];   // 65 KB -> 2 blocks/CU
    const int tid = threadIdx.x;
    const long s = (long)blockIdx.x * 256 + tid;
    if (s >= (long)B_SZ * F_FR) return;   // no __syncthreads in kernel: safe
    const int b = (int)(s / F_FR);
    const int f = (int)(s % F_FR);
    const float* xp = x + (long)b * T_SZ + f * 16;

    float h[GHID];
    float* hl = &hbuf[tid * 65];
#pragma unroll
    for (int k = 0; k < GHID; ++k) { h[k] = 0.0f; hl[k] = 0.0f; }

#pragma unroll 1
    for (int t = 0; t < 32; ++t) {
        const float xt = xp[t];
#pragma unroll 1
        for (int j = 0; j < GHID; ++j) {
            float aR = b_hh[j], aZ = b_hh[GHID + j], aN = b_hh[2 * GHID + j];
            const float* wR = w_hh + j * GHID;
            const float* wZ = w_hh + (GHID + j) * GHID;
            const float* wN = w_hh + (2 * GHID + j) * GHID;
#pragma unroll
            for (int k = 0; k < GHID; ++k) {
                aR = fmaf(wR[k], h[k], aR);
                aZ = fmaf(wZ[k], h[k], aZ);
                aN = fmaf(wN[k], h[k], aN);
            }
            const float ir  = fmaf(xt, w_ih[j],            b_ih[j]);
            const float iz  = fmaf(xt, w_ih[GHID + j],     b_ih[GHID + j]);
            const float inn = fmaf(xt, w_ih[2 * GHID + j], b_ih[2 * GHID + j]);
            const float r = sigm(ir + aR);
            const float z = sigm(iz + aZ);
            const float n = tanh_fast(fmaf(r, aN, inn));
            const float ho = hl[j];          // OLD h[j] (runtime index -> LDS)
            hl[j] = n + z * (ho - n);        // write NEW h[j]
        }
#pragma unroll
        for (int k = 0; k < GHID; ++k) h[k] = hl[k];  // regs <- new h
    }

    // eps = hT @ w_sl.T + b_sl ; A = sigmoid(eps[:8]), g = eps[8:]
    float* outp = ag + s * 16;
#pragma unroll
    for (int o = 0; o < 16; ++o) {
        float e = b_sl[o];
        const float* wr = w_sl + o * GHID;
#pragma unroll
        for (int k = 0; k < GHID; ++k) e = fmaf(wr[k], h[k], e);
        outp[o] = (o < HID) ? sigm(e) : e;
    }
}

// ---------------- Pass 2a: fast-scan chunk summaries ----------------
// One thread per (b, chunk): local scan with h0=0 giving H, and P = prod(A).
// Frame gates constant over aligned 16-step groups -> reload every 16 t.
__global__ __launch_bounds__(256) void fast_chunk(
    const float* __restrict__ x, const float* __restrict__ ag,
    const float* __restrict__ w_in,
    float* __restrict__ chP, float* __restrict__ chH)
{
    const int tid = blockIdx.x * 256 + threadIdx.x;  // tid = b*NCH + c
    const int b = tid / NCH, c = tid % NCH;
    float h[HID], P[HID];
#pragma unroll
    for (int i = 0; i < HID; ++i) { h[i] = 0.0f; P[i] = 1.0f; }
    const float* xp = x + (long)b * T_SZ + c * CHUNK;

#pragma unroll 1
    for (int g = 0; g < CHUNK / 16; ++g) {
        const int t0 = c * CHUNK + g * 16;
        int fr = t0 / 16 - 1; fr = max(0, min(F_FR - 1, fr));
        const float4* agp = (const float4*)(ag + ((long)b * F_FR + fr) * 16);
        const float4 a0 = agp[0], a1 = agp[1], g0 = agp[2], g1 = agp[3];
        const float A[HID]  = {a0.x, a0.y, a0.z, a0.w, a1.x, a1.y, a1.z, a1.w};
        const float Gv[HID] = {g0.x, g0.y, g0.z, g0.w, g1.x, g1.y, g1.z, g1.w};
        float wg[HID];
#pragma unroll
        for (int i = 0; i < HID; ++i) wg[i] = w_in[i] * Gv[i];
#pragma unroll
        for (int tt = 0; tt < 16; ++tt) {
            const float xt = xp[g * 16 + tt];
#pragma unroll
            for (int i = 0; i < HID; ++i) h[i] = fmaf(A[i], h[i], xt * wg[i]);
        }
#pragma unroll
        for (int i = 0; i < HID; ++i) {   // P *= A^16 via squarings
            const float a2 = A[i] * A[i]; const float a4 = a2 * a2; const float a8 = a4 * a4;
            P[i] *= a8 * a8;
        }
    }
    float* pp = chP + (long)tid * HID;
    float* hp = chH + (long)tid * HID;
#pragma unroll
    for (int i = 0; i < HID; ++i) { pp[i] = P[i]; hp[i] = h[i]; }
}

// ---------------- Pass 2b: scan over chunks ----------------
// One thread per (b, hid): h_start(c) sequence over 256 chunks.
__global__ __launch_bounds__(256) void chunk_scan(
    const float* __restrict__ chP, const float* __restrict__ chH,
    float* __restrict__ st)
{
    const int tid = blockIdx.x * 256 + threadIdx.x;
    if (tid >= B_SZ * HID) return;
    const int b = tid / HID, i = tid % HID;
    float h = 0.0f;
#pragma unroll 1
    for (int c = 0; c < NCH; ++c) {
        const long idx = ((long)b * NCH + c) * HID + i;
        st[idx] = h;                       // h at chunk start
        h = fmaf(chP[idx], h, chH[idx]);
    }
}

// ---------------- Pass 2c: apply + output ----------------
// One thread per (b, chunk): redo local scan seeded with true h0, emit y.
__global__ __launch_bounds__(256) void fast_apply(
    const float* __restrict__ x, const float* __restrict__ ag,
    const float* __restrict__ w_in, const float* __restrict__ w_out,
    const float* __restrict__ st, float* __restrict__ y)
{
    const int tid = blockIdx.x * 256 + threadIdx.x;  // tid = b*NCH + c
    const int b = tid / NCH, c = tid % NCH;
    float h[HID];
    const float* sp = st + (long)tid * HID;
#pragma unroll
    for (int i = 0; i < HID; ++i) h[i] = sp[i];
    float wo[HID];
#pragma unroll
    for (int i = 0; i < HID; ++i) wo[i] = w_out[i];
    const float* xp = x + (long)b * T_SZ + c * CHUNK;
    float* yp = y + (long)b * T_SZ + c * CHUNK;

#pragma unroll 1
    for (int g = 0; g < CHUNK / 16; ++g) {
        const int t0 = c * CHUNK + g * 16;
        int fr = t0 / 16 - 1; fr = max(0, min(F_FR - 1, fr));
        const float4* agp = (const float4*)(ag + ((long)b * F_FR + fr) * 16);
        const float4 a0 = agp[0], a1 = agp[1], g0 = agp[2], g1 = agp[3];
        const float A[HID]  = {a0.x, a0.y, a0.z, a0.w, a1.x, a1.y, a1.z, a1.w};
        const float Gv[HID] = {g0.x, g0.y, g0.z, g0.w, g1.x, g1.y, g1.z, g1.w};
        float wg[HID];
#pragma unroll
        for (int i = 0; i < HID; ++i) wg[i] = w_in[i] * Gv[i];
#pragma unroll
        for (int tt = 0; tt < 16; ++tt) {
            const float xt = xp[g * 16 + tt];
            float acc = 0.0f;
#pragma unroll
            for (int i = 0; i < HID; ++i) {
                h[i] = fmaf(A[i], h[i], xt * wg[i]);
                acc = fmaf(h[i], wo[i], acc);
            }
            yp[g * 16 + tt] = acc;
        }
    }
}

extern "C" void kernel_launch(void* const* d_in, const int* in_sizes, int n_in,
                              void* d_out, int out_size, void* d_ws, size_t ws_size,
                              hipStream_t stream) {
    const float* x    = (const float*)d_in[0];
    const float* w_in = (const float*)d_in[1];
    const float* w_out= (const float*)d_in[2];
    const float* w_ih = (const float*)d_in[3];
    const float* w_hh = (const float*)d_in[4];
    const float* b_ih = (const float*)d_in[5];
    const float* b_hh = (const float*)d_in[6];
    const float* w_sl = (const float*)d_in[7];
    const float* b_sl = (const float*)d_in[8];
    float* y = (float*)d_out;

    // Workspace layout (floats): ag[B][F][16] | chP[B][NCH][8] | chH | st
    float* ag  = (float*)d_ws;
    size_t off = (size_t)B_SZ * F_FR * 16;            // 8,386,560
    float* chP = ag + off;
    float* chH = chP + (size_t)B_SZ * NCH * HID;      // 262,144 each
    float* st  = chH + (size_t)B_SZ * NCH * HID;      // total ~36.7 MB

    const int nseq = B_SZ * F_FR;                      // 524,160
    gru_slow<<<(nseq + 255) / 256, 256, 0, stream>>>(x, w_ih, w_hh, b_ih, b_hh, w_sl, b_sl, ag);
    fast_chunk<<<(B_SZ * NCH) / 256, 256, 0, stream>>>(x, ag, w_in, chP, chH);
    chunk_scan<<<(B_SZ * HID + 255) / 256, 256, 0, stream>>>(chP, chH, st);
    fast_apply<<<(B_SZ * NCH) / 256, 256, 0, stream>>>(x, ag, w_in, w_out, st, y);
}

// Round 3
// 1293.475 us; speedup vs baseline: 7.5924x; 7.5924x over previous
//
#include <hip/hip_runtime.h>
#include <hip/hip_bf16.h>
#include <math.h>

// Problem constants (from reference)
#define B_SZ 128
#define T_SZ 65536
#define F_FR 4095          // (T - 32)/16 + 1
#define GHID 64            // GRU hidden
#define HID 8
#define CHUNK 256          // fast-scan chunk length
#define NCH (T_SZ / CHUNK) // 256 chunks

typedef _Float16 half8 __attribute__((ext_vector_type(8)));
typedef float f32x4 __attribute__((ext_vector_type(4)));

#define L2E 1.4426950408889634f

static __device__ __forceinline__ float frcp(float v) {
#if __has_builtin(__builtin_amdgcn_rcpf)
    return __builtin_amdgcn_rcpf(v);
#else
    return 1.0f / v;
#endif
}
static __device__ __forceinline__ float fexp2(float v) {
#if __has_builtin(__builtin_amdgcn_exp2f)
    return __builtin_amdgcn_exp2f(v);
#else
    return exp2f(v);
#endif
}
__device__ __forceinline__ float sigm(float xv) { return frcp(1.0f + fexp2(-L2E * xv)); }

#define FSTR 68   // h-mirror row stride (floats): 68%32=4 -> 2-way banks (free)
#define XSTR 33   // x-stage row stride

// ---------------- Pass 1: per-frame GRU via MFMA ----------------
// 4 independent waves/block; each wave owns 16 sequences (tile).
// Per step: C[16 seq][192 gates] = H(16x64, f16 hi+lo) * W_hh^T(64x192, f16),
// 12 N-tiles x 2 K-chunks x 2 products = 48 mfma_f32_16x16x32_f16.
// W pre-scaled: R/Z rows by -log2e, N rows by 2*log2e, so sigmoid/tanh use
// exp2 directly with no range multiply.
// CRITICAL (round-2 bugfix): reference n = tanh(inn + r*hn) with
// hn = W_n.h + b_hh_n -> b_hh_n is INSIDE the r product. Keep it as a
// separate per-lane constant added to the MFMA result BEFORE multiplying
// by r; only b_ih folds additively. (R/Z gates: both biases fold.)
// h state: f32 in per-wave LDS double buffer [seq][j] + lane-local ho regs
// in C-layout. A/B k-mapping errors cancel (same map used for both
// operands); C/D layout is HW-verified col=lane&15, row=(lane>>4)*4+reg.
__global__ __launch_bounds__(256, 2) void gru_mfma(
    const float* __restrict__ x, const float* __restrict__ w_ih,
    const float* __restrict__ w_hh, const float* __restrict__ b_ih,
    const float* __restrict__ b_hh, const float* __restrict__ w_sl,
    const float* __restrict__ b_sl, float* __restrict__ ag)
{
    __shared__ float lds[4][2 * 16 * FSTR + 16 * XSTR];  // 43.3 KB/block
    const int tid  = threadIdx.x;
    const int wv   = tid >> 6;
    const int lane = tid & 63;
    const int c16  = lane & 15;   // B-col (gate-in-tile) / A-row (seq)
    const int g    = lane >> 4;   // 16-lane group (k-group; C row-group)
    float* hb0 = &lds[wv][0];
    float* hb1 = hb0 + 16 * FSTR;
    float* xs  = hb1 + 16 * FSTR;
    const int tile = ((int)blockIdx.x * 4 + wv) * 16;

    // ---- resident B-frags: W_hh^T (f16, pre-scaled) ----
    half8 wf[12][2];
#pragma unroll
    for (int n = 0; n < 12; ++n) {
        const float sc = (n < 8) ? -L2E : (2.0f * L2E);
        const int gate = 16 * n + c16;
#pragma unroll
        for (int c = 0; c < 2; ++c) {
            const float4 q0 = *(const float4*)(w_hh + gate * 64 + 32 * c + 8 * g);
            const float4 q1 = *(const float4*)(w_hh + gate * 64 + 32 * c + 8 * g + 4);
            wf[n][c][0] = (_Float16)(sc * q0.x); wf[n][c][1] = (_Float16)(sc * q0.y);
            wf[n][c][2] = (_Float16)(sc * q0.z); wf[n][c][3] = (_Float16)(sc * q0.w);
            wf[n][c][4] = (_Float16)(sc * q1.x); wf[n][c][5] = (_Float16)(sc * q1.y);
            wf[n][c][6] = (_Float16)(sc * q1.z); wf[n][c][7] = (_Float16)(sc * q1.w);
        }
    }

    // ---- per-lane gate constants (4 gates j = c16 + 16m) ----
    float wiR[4], wiZ[4], wiN[4], bR[4], bZ[4], biN[4], bhN[4];
#pragma unroll
    for (int m = 0; m < 4; ++m) {
        const int j = c16 + 16 * m;
        wiR[m] = -L2E * w_ih[j];
        wiZ[m] = -L2E * w_ih[64 + j];
        wiN[m] = 2.0f * L2E * w_ih[128 + j];
        bR[m]  = -L2E * (b_ih[j] + b_hh[j]);
        bZ[m]  = -L2E * (b_ih[64 + j] + b_hh[64 + j]);
        biN[m] = 2.0f * L2E * b_ih[128 + j];          // additive part only
        bhN[m] = 2.0f * L2E * b_hh[128 + j];          // multiplied by r
    }

    // ---- stage x[16 seq][32 t] into LDS; zero h buffer 0 ----
    {
        const int s = tile + c16;
        const int b = s / F_FR;
        const int f = s % F_FR;
        const float* xp = x + (long)b * T_SZ + f * 16;
#pragma unroll
        for (int k = 0; k < 8; ++k) xs[c16 * XSTR + g * 8 + k] = xp[g * 8 + k];
    }
#pragma unroll
    for (int m = 0; m < 4; ++m)
#pragma unroll
        for (int r = 0; r < 4; ++r) hb0[(4 * g + r) * FSTR + (c16 + 16 * m)] = 0.0f;
    __syncthreads();

    const f32x4 zz = {0.0f, 0.0f, 0.0f, 0.0f};
    float ho[4][4];
#pragma unroll
    for (int m = 0; m < 4; ++m)
#pragma unroll
        for (int r = 0; r < 4; ++r) ho[m][r] = 0.0f;

#pragma unroll 2
    for (int t = 0; t < 32; ++t) {
        float* hr_ = (t & 1) ? hb1 : hb0;   // read (state before step t)
        float* hw_ = (t & 1) ? hb0 : hb1;   // write (state after step t)

        // A-frags (H hi/lo) from LDS
        half8 ah[2], al[2];
#pragma unroll
        for (int c = 0; c < 2; ++c) {
            const float* rp = hr_ + c16 * FSTR + 32 * c + 8 * g;
            const float4 u0 = *(const float4*)rp;
            const float4 u1 = *(const float4*)(rp + 4);
            const float fv[8] = {u0.x, u0.y, u0.z, u0.w, u1.x, u1.y, u1.z, u1.w};
#pragma unroll
            for (int e = 0; e < 8; ++e) {
                const _Float16 hi = (_Float16)fv[e];
                ah[c][e] = hi;
                al[c][e] = (_Float16)(fv[e] - (float)hi);
            }
        }

        f32x4 acc[12];
#pragma unroll
        for (int n = 0; n < 12; ++n) {
            f32x4 a = __builtin_amdgcn_mfma_f32_16x16x32_f16(ah[0], wf[n][0], zz, 0, 0, 0);
            a = __builtin_amdgcn_mfma_f32_16x16x32_f16(al[0], wf[n][0], a, 0, 0, 0);
            a = __builtin_amdgcn_mfma_f32_16x16x32_f16(ah[1], wf[n][1], a, 0, 0, 0);
            acc[n] = __builtin_amdgcn_mfma_f32_16x16x32_f16(al[1], wf[n][1], a, 0, 0, 0);
        }

        float xt4[4];
#pragma unroll
        for (int r = 0; r < 4; ++r) xt4[r] = xs[(4 * g + r) * XSTR + t];

#pragma unroll
        for (int m = 0; m < 4; ++m) {
            const int jm = c16 + 16 * m;
#pragma unroll
            for (int r = 0; r < 4; ++r) {
                // uR = -log2e*(ir+hr) ; r = 1/(1+2^uR) = sigmoid(ir+hr)
                const float uR = fmaf(xt4[r], wiR[m], bR[m]) + acc[m][r];
                const float rr = frcp(1.0f + fexp2(uR));
                const float uZ = fmaf(xt4[r], wiZ[m], bZ[m]) + acc[4 + m][r];
                const float zf = frcp(1.0f + fexp2(uZ));
                // uN = 2log2e*(inn + r*(Wn.h + b_hh_n)) ; n = tanh(.)
                const float uN = fmaf(rr, acc[8 + m][r] + bhN[m],
                                      fmaf(xt4[r], wiN[m], biN[m]));
                const float nn = fmaf(-2.0f, frcp(1.0f + fexp2(uN)), 1.0f);
                const float hnew = fmaf(zf, ho[m][r] - nn, nn);
                ho[m][r] = hnew;
                hw_[(4 * g + r) * FSTR + jm] = hnew;
            }
        }
        __syncthreads();
    }

    // ---- epilogue: eps = hT @ w_sl^T + b_sl (final h is in hb0) ----
    half8 fh[2], fl[2];
#pragma unroll
    for (int c = 0; c < 2; ++c) {
        const float* rp = hb0 + c16 * FSTR + 32 * c + 8 * g;
        const float4 u0 = *(const float4*)rp;
        const float4 u1 = *(const float4*)(rp + 4);
        const float fv[8] = {u0.x, u0.y, u0.z, u0.w, u1.x, u1.y, u1.z, u1.w};
#pragma unroll
        for (int e = 0; e < 8; ++e) {
            const _Float16 hi = (_Float16)fv[e];
            fh[c][e] = hi;
            fl[c][e] = (_Float16)(fv[e] - (float)hi);
        }
    }
    half8 wsl[2];
#pragma unroll
    for (int c = 0; c < 2; ++c) {
        const float4 q0 = *(const float4*)(w_sl + c16 * 64 + 32 * c + 8 * g);
        const float4 q1 = *(const float4*)(w_sl + c16 * 64 + 32 * c + 8 * g + 4);
        wsl[c][0] = (_Float16)q0.x; wsl[c][1] = (_Float16)q0.y;
        wsl[c][2] = (_Float16)q0.z; wsl[c][3] = (_Float16)q0.w;
        wsl[c][4] = (_Float16)q1.x; wsl[c][5] = (_Float16)q1.y;
        wsl[c][6] = (_Float16)q1.z; wsl[c][7] = (_Float16)q1.w;
    }
    f32x4 ec = __builtin_amdgcn_mfma_f32_16x16x32_f16(fh[0], wsl[0], zz, 0, 0, 0);
    ec = __builtin_amdgcn_mfma_f32_16x16x32_f16(fl[0], wsl[0], ec, 0, 0, 0);
    ec = __builtin_amdgcn_mfma_f32_16x16x32_f16(fh[1], wsl[1], ec, 0, 0, 0);
    ec = __builtin_amdgcn_mfma_f32_16x16x32_f16(fl[1], wsl[1], ec, 0, 0, 0);
    const float bs = b_sl[c16];
#pragma unroll
    for (int r = 0; r < 4; ++r) {
        float e = ec[r] + bs;
        if (c16 < 8) e = sigm(e);            // A_s = sigmoid(eps[:8]); g_s raw
        ag[(long)(tile + 4 * g + r) * 16 + c16] = e;
    }
}

// ---------------- Pass 2a: fast-scan chunk summaries ----------------
__global__ __launch_bounds__(256) void fast_chunk(
    const float* __restrict__ x, const float* __restrict__ ag,
    const float* __restrict__ w_in,
    float* __restrict__ chP, float* __restrict__ chH)
{
    const int tid = blockIdx.x * 256 + threadIdx.x;  // tid = b*NCH + c
    const int b = tid / NCH, c = tid % NCH;
    float h[HID], P[HID];
#pragma unroll
    for (int i = 0; i < HID; ++i) { h[i] = 0.0f; P[i] = 1.0f; }
    const float* xp = x + (long)b * T_SZ + c * CHUNK;

#pragma unroll 1
    for (int g = 0; g < CHUNK / 16; ++g) {
        const int t0 = c * CHUNK + g * 16;
        int fr = t0 / 16 - 1; fr = max(0, min(F_FR - 1, fr));
        const float4* agp = (const float4*)(ag + ((long)b * F_FR + fr) * 16);
        const float4 a0 = agp[0], a1 = agp[1], g0 = agp[2], g1 = agp[3];
        const float A[HID]  = {a0.x, a0.y, a0.z, a0.w, a1.x, a1.y, a1.z, a1.w};
        const float Gv[HID] = {g0.x, g0.y, g0.z, g0.w, g1.x, g1.y, g1.z, g1.w};
        float wg[HID];
#pragma unroll
        for (int i = 0; i < HID; ++i) wg[i] = w_in[i] * Gv[i];
#pragma unroll
        for (int tt = 0; tt < 16; ++tt) {
            const float xt = xp[g * 16 + tt];
#pragma unroll
            for (int i = 0; i < HID; ++i) h[i] = fmaf(A[i], h[i], xt * wg[i]);
        }
#pragma unroll
        for (int i = 0; i < HID; ++i) {
            const float a2 = A[i] * A[i]; const float a4 = a2 * a2; const float a8 = a4 * a4;
            P[i] *= a8 * a8;
        }
    }
    float* pp = chP + (long)tid * HID;
    float* hp = chH + (long)tid * HID;
#pragma unroll
    for (int i = 0; i < HID; ++i) { pp[i] = P[i]; hp[i] = h[i]; }
}

// ---------------- Pass 2b: scan over chunks ----------------
__global__ __launch_bounds__(256) void chunk_scan(
    const float* __restrict__ chP, const float* __restrict__ chH,
    float* __restrict__ st)
{
    const int tid = blockIdx.x * 256 + threadIdx.x;
    if (tid >= B_SZ * HID) return;
    const int b = tid / HID, i = tid % HID;
    float h = 0.0f;
#pragma unroll 1
    for (int c = 0; c < NCH; ++c) {
        const long idx = ((long)b * NCH + c) * HID + i;
        st[idx] = h;
        h = fmaf(chP[idx], h, chH[idx]);
    }
}

// ---------------- Pass 2c: apply + output ----------------
__global__ __launch_bounds__(256) void fast_apply(
    const float* __restrict__ x, const float* __restrict__ ag,
    const float* __restrict__ w_in, const float* __restrict__ w_out,
    const float* __restrict__ st, float* __restrict__ y)
{
    const int tid = blockIdx.x * 256 + threadIdx.x;  // tid = b*NCH + c
    const int b = tid / NCH, c = tid % NCH;
    float h[HID];
    const float* sp = st + (long)tid * HID;
#pragma unroll
    for (int i = 0; i < HID; ++i) h[i] = sp[i];
    float wo[HID];
#pragma unroll
    for (int i = 0; i < HID; ++i) wo[i] = w_out[i];
    const float* xp = x + (long)b * T_SZ + c * CHUNK;
    float* yp = y + (long)b * T_SZ + c * CHUNK;

#pragma unroll 1
    for (int g = 0; g < CHUNK / 16; ++g) {
        const int t0 = c * CHUNK + g * 16;
        int fr = t0 / 16 - 1; fr = max(0, min(F_FR - 1, fr));
        const float4* agp = (const float4*)(ag + ((long)b * F_FR + fr) * 16);
        const float4 a0 = agp[0], a1 = agp[1], g0 = agp[2], g1 = agp[3];
        const float A[HID]  = {a0.x, a0.y, a0.z, a0.w, a1.x, a1.y, a1.z, a1.w};
        const float Gv[HID] = {g0.x, g0.y, g0.z, g0.w, g1.x, g1.y, g1.z, g1.w};
        float wg[HID];
#pragma unroll
        for (int i = 0; i < HID; ++i) wg[i] = w_in[i] * Gv[i];
#pragma unroll
        for (int tt = 0; tt < 16; ++tt) {
            const float xt = xp[g * 16 + tt];
            float acc = 0.0f;
#pragma unroll
            for (int i = 0; i < HID; ++i) {
                h[i] = fmaf(A[i], h[i], xt * wg[i]);
                acc = fmaf(h[i], wo[i], acc);
            }
            yp[g * 16 + tt] = acc;
        }
    }
}

extern "C" void kernel_launch(void* const* d_in, const int* in_sizes, int n_in,
                              void* d_out, int out_size, void* d_ws, size_t ws_size,
                              hipStream_t stream) {
    const float* x    = (const float*)d_in[0];
    const float* w_in = (const float*)d_in[1];
    const float* w_out= (const float*)d_in[2];
    const float* w_ih = (const float*)d_in[3];
    const float* w_hh = (const float*)d_in[4];
    const float* b_ih = (const float*)d_in[5];
    const float* b_hh = (const float*)d_in[6];
    const float* w_sl = (const float*)d_in[7];
    const float* b_sl = (const float*)d_in[8];
    float* y = (float*)d_out;

    // Workspace layout (floats): ag[B][F][16] | chP[B][NCH][8] | chH | st
    float* ag  = (float*)d_ws;
    size_t off = (size_t)B_SZ * F_FR * 16;            // 8,386,560
    float* chP = ag + off;
    float* chH = chP + (size_t)B_SZ * NCH * HID;      // 262,144 each
    float* st  = chH + (size_t)B_SZ * NCH * HID;      // total ~36.7 MB

    const int nseq = B_SZ * F_FR;                      // 524,160 = 8190*64
    gru_mfma<<<nseq / 64, 256, 0, stream>>>(x, w_ih, w_hh, b_ih, b_hh, w_sl, b_sl, ag);
    fast_chunk<<<(B_SZ * NCH) / 256, 256, 0, stream>>>(x, ag, w_in, chP, chH);
    chunk_scan<<<(B_SZ * HID + 255) / 256, 256, 0, stream>>>(chP, chH, st);
    fast_apply<<<(B_SZ * NCH) / 256, 256, 0, stream>>>(x, ag, w_in, w_out, st, y);
}